// Round 1
// baseline (282.466 us; speedup 1.0000x reference)
//
#include <hip/hip_runtime.h>

// y = x @ W^T + bias; x:[65536,512] f32, W:[512,512] f32, bias:[512] f32.
// bf16 MFMA 16x16x32, fp32 accumulate. 128x128 tile, BK=64, 4 waves.
// R3: double-buffered LDS + raw s_barrier with lgkmcnt-only wait.
//   __syncthreads() drains vmcnt(0) (barrier-drain stall, m97 structure);
//   replacing it with {s_waitcnt lgkmcnt(0); s_barrier} keeps the global
//   prefetch for tile i+2 in flight across the barrier and the whole MFMA
//   phase of iter i+1. One barrier per K-step instead of two.

#define BM 128
#define BN 128
#define BK 64
#define ABK 72  // 144 B row stride = 36 banks -> <=2-way conflicts (free per m136)

typedef __bf16 bf16x8 __attribute__((ext_vector_type(8)));
typedef float f32x4 __attribute__((ext_vector_type(4)));

__global__ __launch_bounds__(256, 2)
void linear_bf16_mfma(const float* __restrict__ X,
                      const float* __restrict__ W,
                      const float* __restrict__ bias,
                      float* __restrict__ Y) {
  constexpr int K = 512;
  constexpr int N = 512;

  __shared__ __bf16 As[2][BM * ABK];
  __shared__ __bf16 Bs[2][BN * ABK];

  const int tid  = threadIdx.x;
  const int lane = tid & 63;
  const int wave = tid >> 6;

  // XCD-locality swizzle: the 4 blocks sharing one X row-tile get linear ids
  // differing by 8 -> same XCD under round-robin dispatch -> X re-reads are
  // L2 hits instead of HBM re-fetches.
  const int lid = blockIdx.x;          // 0..2047
  const int xcd = lid & 7;
  const int ii  = lid >> 3;            // 0..255
  const int nt  = ii & 3;
  const int mt  = (ii >> 2) * 8 + xcd; // 0..511
  const int bm = mt * BM;
  const int bn = nt * BN;

  const int wm = (wave >> 1) * 64;
  const int wn = (wave & 1) * 64;

  // staging: thread t -> row (t>>3)+32p, k-cols (t&7)*8..+7 (32 B contiguous)
  const int srow = tid >> 3;
  const int scol = (tid & 7) * 8;

  // MFMA A/B fragment: row = lane&15, k = (lane>>4)*8 + j
  const int mrow = lane & 15;
  const int kq   = (lane >> 4) * 8;

  const float* Xp = X + (size_t)(bm + srow) * K + scol;
  const float* Wp = W + (size_t)(bn + srow) * K + scol;

  f32x4 xa[4][2], wb[4][2];

  auto load_tile = [&](int k0) {
#pragma unroll
    for (int p = 0; p < 4; ++p) {
      const float* ga = Xp + (size_t)p * 32 * K + k0;
      xa[p][0] = *(const f32x4*)ga;
      xa[p][1] = *(const f32x4*)(ga + 4);
      const float* gb = Wp + (size_t)p * 32 * K + k0;
      wb[p][0] = *(const f32x4*)gb;
      wb[p][1] = *(const f32x4*)(gb + 4);
    }
  };

  auto cvt_write = [&](int c) {
#pragma unroll
    for (int p = 0; p < 4; ++p) {
      bf16x8 av, bv;
#pragma unroll
      for (int e = 0; e < 4; ++e) {
        av[e]     = (__bf16)xa[p][0][e];
        av[e + 4] = (__bf16)xa[p][1][e];
        bv[e]     = (__bf16)wb[p][0][e];
        bv[e + 4] = (__bf16)wb[p][1][e];
      }
      const int r = p * 32 + srow;
      *(bf16x8*)(&As[c][r * ABK + scol]) = av;
      *(bf16x8*)(&Bs[c][r * ABK + scol]) = bv;
    }
  };

  f32x4 acc[4][4] = {};

  // prologue: tile 0 -> LDS buf0; tile 1 loads left in flight across barrier
  load_tile(0);
  cvt_write(0);                       // compiler-inserted vmcnt waits
  load_tile(BK);                      // tile 1 -> regs, stays in flight
  asm volatile("s_waitcnt lgkmcnt(0)" ::: "memory");
  __builtin_amdgcn_s_barrier();
  __builtin_amdgcn_sched_barrier(0);

  int c = 0;
  for (int i = 0; i < 8; ++i) {
    // MFMA phase on buf[c] (tile i); tile i+1 loads still in flight
#pragma unroll
    for (int ks = 0; ks < BK; ks += 32) {
      bf16x8 af[4], bfr[4];
#pragma unroll
      for (int i2 = 0; i2 < 4; ++i2)
        af[i2] = *(const bf16x8*)(&As[c][(wm + i2 * 16 + mrow) * ABK + ks + kq]);
#pragma unroll
      for (int j = 0; j < 4; ++j)
        bfr[j] = *(const bf16x8*)(&Bs[c][(wn + j * 16 + mrow) * ABK + ks + kq]);
#pragma unroll
      for (int i2 = 0; i2 < 4; ++i2)
#pragma unroll
        for (int j = 0; j < 4; ++j)
          acc[i2][j] = __builtin_amdgcn_mfma_f32_16x16x32_bf16(af[i2], bfr[j],
                                                               acc[i2][j], 0, 0, 0);
    }
    if (i < 7) {
      cvt_write(c ^ 1);               // tile i+1: counted vmcnt waits here only
      if (i < 6) load_tile((i + 2) * BK);  // tile i+2 -> regs, in flight
      // barrier WITHOUT vmcnt drain: only LDS writes must be visible
      asm volatile("s_waitcnt lgkmcnt(0)" ::: "memory");
      __builtin_amdgcn_s_barrier();
      __builtin_amdgcn_sched_barrier(0);
      c ^= 1;
    }
  }

  // epilogue: C/D layout col=lane&15 (n), row=(lane>>4)*4+reg (m)
  const int col0 = lane & 15;
  const int row0 = (lane >> 4) * 4;
#pragma unroll
  for (int j = 0; j < 4; ++j) {
    const int gc = bn + wn + j * 16 + col0;
    const float bj = bias[gc];
#pragma unroll
    for (int i2 = 0; i2 < 4; ++i2) {
      const int gr = bm + wm + i2 * 16 + row0;
#pragma unroll
      for (int r = 0; r < 4; ++r)
        __builtin_nontemporal_store(acc[i2][j][r] + bj,
                                    &Y[(size_t)(gr + r) * N + gc]);
    }
  }
}

extern "C" void kernel_launch(void* const* d_in, const int* in_sizes, int n_in,
                              void* d_out, int out_size, void* d_ws, size_t ws_size,
                              hipStream_t stream) {
  const float* X = (const float*)d_in[0];
  const float* W = (const float*)d_in[1];
  const float* b = (const float*)d_in[2];
  float* Y = (float*)d_out;
  linear_bf16_mfma<<<dim3(2048), 256, 0, stream>>>(X, W, b, Y);
}